// Round 19
// baseline (96.640 us; speedup 1.0000x reference)
//
#include <hip/hip_runtime.h>
#include <math.h>

#define BB 16
#define TT 128
#define MM 32
#define PP 64
#define CC 256

typedef float f32x4 __attribute__((ext_vector_type(4)));

// Fused kernel: 512 blocks x 256 threads, __launch_bounds__(256,2) -> 2 blocks/CU
// guaranteed co-resident (512 total) => per-batch atomic barrier is safe.
// Block g: (b = g>>5, m = g&31).
//   Phase 1: w_in, eff_c (LDS + nrm LDS), eff_p, out_c = mem[m]@eff_c, MLP.
//   Barrier on cnt[b] == 32 (R13's proven fence pattern).
//   Phase 2: wout row m, eoc (256 c), stream module m for batch b (4 chunks).
// All 16 b-blocks of module m map to XCD m%8 -> phase-2 reads are L2-hot.
__global__ __launch_bounds__(256, 2) void KF(
        const float* __restrict__ pointers,
        const float* __restrict__ contents,
        const float* __restrict__ receivers,
        const float* __restrict__ memories,
        const float* __restrict__ W1,
        const float* __restrict__ b1,
        const float* __restrict__ W2,
        const float* __restrict__ b2,
        float* __restrict__ outp_g,
        float* __restrict__ outc_g,
        float* __restrict__ mems_out,
        int* __restrict__ cnt) {
    const int g = blockIdx.x;
    const int b = g >> 5, m = g & 31;
    const int tid = threadIdx.x;
    const int lane = tid & 63, w = tid >> 6;     // 4 waves

    __shared__ float w_in[TT];
    __shared__ __align__(16) float ri[PP + CC];  // [eff_p | eff_c]
    __shared__ float part4[4][PP];
    __shared__ float h[PP];
    __shared__ float outc_s[CC];
    __shared__ float red[4];
    __shared__ __align__(16) float op_s[PP];
    __shared__ float wout_s[MM];
    __shared__ __align__(16) float nrm_s[CC];
    __shared__ float eoc_s[CC];

    // ================= phase 1 =================
    // w_in: 2 lanes per token
    {
        const int t = tid >> 1, q = tid & 1;
        const float4* pr4 = reinterpret_cast<const float4*>(pointers + (b * TT + t) * PP + q * 32);
        const float4* rc4 = reinterpret_cast<const float4*>(receivers + m * PP + q * 32);
        float s = 0.f;
        #pragma unroll
        for (int k = 0; k < 8; ++k) {
            float4 v = pr4[k], rv = rc4[k];
            s += v.x * rv.x + v.y * rv.y + v.z * rv.z + v.w * rv.w;
        }
        s += __shfl_xor(s, 1, 64);
        if (q == 0) {
            float th = tanhf(s);
            w_in[t] = th > 0.f ? th : 0.f;
        }
    }
    __syncthreads();
    // eff_c: c = tid, full 128-token loop (coalesced 1KB-stride loads)
    float ecv;
    {
        float acc = 0.f;
        const float* cb = contents + b * TT * CC + tid;
        #pragma unroll 8
        for (int t = 0; t < TT; ++t) acc += w_in[t] * cb[t * CC];
        ri[PP + tid] = acc;
        ecv = acc;
        float v = ecv * ecv;
        #pragma unroll
        for (int off = 32; off; off >>= 1) v += __shfl_xor(v, off, 64);
        if (lane == 0) red[w] = v;
    }
    // eff_p partials: p = tid&63, 4 t-groups of 32
    {
        const int p = tid & 63, gq = tid >> 6;
        const float* pb = pointers + (b * TT + gq * 32) * PP + p;
        float acc = 0.f;
        #pragma unroll
        for (int t = 0; t < 32; ++t) acc += w_in[gq * 32 + t] * pb[t * PP];
        part4[gq][p] = acc;
    }
    __syncthreads();
    if (tid < PP)
        ri[tid] = part4[0][tid] + part4[1][tid] + part4[2][tid] + part4[3][tid];
    nrm_s[tid] = ecv / (red[0] + red[1] + red[2] + red[3] + 1e-42f);
    __syncthreads();

    // out_c = mem[m] @ eff_c: wave w rows w*64 + i*4 + gg, 16 lanes/row
    {
        const int gg = lane >> 4, j = lane & 15;
        float4 e_reg[4];
        #pragma unroll
        for (int k = 0; k < 4; ++k)
            e_reg[k] = *reinterpret_cast<const float4*>(&ri[PP + 4 * (j + 16 * k)]);
        const float4* mem4 = reinterpret_cast<const float4*>(memories) + m * (CC * CC / 4);
        #pragma unroll
        for (int i = 0; i < 16; ++i) {
            const int c = w * 64 + i * 4 + gg;
            const float4* row4 = mem4 + c * 64;
            float s = 0.f;
            #pragma unroll
            for (int k = 0; k < 4; ++k) {
                float4 mv = row4[j + 16 * k];
                s += mv.x * e_reg[k].x + mv.y * e_reg[k].y
                   + mv.z * e_reg[k].z + mv.w * e_reg[k].w;
            }
            s += __shfl_xor(s, 1, 64);
            s += __shfl_xor(s, 2, 64);
            s += __shfl_xor(s, 4, 64);
            s += __shfl_xor(s, 8, 64);
            if (j == 0) outc_s[c] = s;
        }
    }

    // MLP layer 1: o = lane, 4 i-segments of 80
    {
        const float* w1 = W1 + m * 320 * 64;
        float acc = 0.f;
        const int i0 = w * 80;
        #pragma unroll 8
        for (int i = i0; i < i0 + 80; ++i) acc += ri[i] * w1[i * 64 + lane];
        __syncthreads();               // also covers outc_s completion
        part4[w][lane] = acc;
    }
    __syncthreads();
    if (tid < PP) {
        float s = part4[0][tid] + part4[1][tid] + part4[2][tid] + part4[3][tid]
                + b1[m * PP + tid];
        h[tid] = s > 0.f ? s : 0.f;
    }
    outc_g[g * CC + tid] = outc_s[tid];
    __syncthreads();
    // MLP layer 2: o = lane, 4 i-segments of 16
    {
        const float* w2 = W2 + m * 64 * 64;
        float acc = 0.f;
        const int i0 = w * 16;
        #pragma unroll
        for (int i = i0; i < i0 + 16; ++i) acc += h[i] * w2[i * 64 + lane];
        part4[w][lane] = acc;
    }
    __syncthreads();
    if (tid < PP) {
        float s = part4[0][tid] + part4[1][tid] + part4[2][tid] + part4[3][tid]
                + b2[m * PP + tid];
        float op = s > 0.f ? s : 0.f;
        op_s[tid] = op;
        outp_g[g * PP + tid] = op;
    }

    // ============ per-batch barrier (R13's proven pattern) ============
    __syncthreads();                   // drains this block's global stores
    if (tid == 0) {
        __threadfence();               // release outp/outc
        atomicAdd(&cnt[b], 1);
        while (__hip_atomic_load(&cnt[b], __ATOMIC_RELAXED,
                                 __HIP_MEMORY_SCOPE_AGENT) < MM) {
            __builtin_amdgcn_s_sleep(8);
        }
        __threadfence();               // acquire siblings' writes
    }
    __syncthreads();

    // ================= phase 2 =================
    // wout row m: n = tid>>3, j = tid&7 (op_m from LDS)
    {
        const int n = tid >> 3, j = tid & 7;
        const float* opm = op_s + j * 8;
        const float* opn = outp_g + (b * MM + n) * PP + j * 8;
        float s = 0.f;
        #pragma unroll
        for (int k = 0; k < 8; ++k) s += opm[k] * opn[k];
        s += __shfl_xor(s, 1, 64);
        s += __shfl_xor(s, 2, 64);
        s += __shfl_xor(s, 4, 64);
        if (j == 0) {
            float th = tanhf(s);
            wout_s[n] = th > 0.f ? th : 0.f;
        }
    }
    __syncthreads();
    // eoc: c = tid, 32 n's (coalesced 1KB-stride loads, L2-hot)
    {
        float acc = 0.f;
        const float* cb = outc_g + b * MM * CC + tid;
        #pragma unroll 8
        for (int n = 0; n < MM; ++n) acc += wout_s[n] * cb[n * CC];
        eoc_s[tid] = acc;
    }
    __syncthreads();

    // stream module m for batch b: 4 chunks x {16 loads, 16 stores}
    const f32x4 nv = *reinterpret_cast<const f32x4*>(&nrm_s[lane * 4]);
    const f32x4* mem4 = reinterpret_cast<const f32x4*>(memories) + m * (CC * CC / 4);
    f32x4* out4 = reinterpret_cast<f32x4*>(mems_out) + g * (CC * CC / 4);
    for (int cq = 0; cq < 4; ++cq) {
        f32x4 mv[16];
        #pragma unroll
        for (int k = 0; k < 16; ++k)
            mv[k] = mem4[cq * 4096 + k * 256 + tid];
        #pragma unroll
        for (int k = 0; k < 16; ++k) {
            const float e = eoc_s[cq * 64 + k * 4 + w];
            f32x4 o;
            o.x = 0.5f * (mv[k].x + e * nv.x);
            o.y = 0.5f * (mv[k].y + e * nv.y);
            o.z = 0.5f * (mv[k].z + e * nv.z);
            o.w = 0.5f * (mv[k].w + e * nv.w);
            out4[cq * 4096 + k * 256 + tid] = o;
        }
    }
}

extern "C" void kernel_launch(void* const* d_in, const int* in_sizes, int n_in,
                              void* d_out, int out_size, void* d_ws, size_t ws_size,
                              hipStream_t stream) {
    const float* pointers  = (const float*)d_in[0];
    const float* contents  = (const float*)d_in[1];
    const float* receivers = (const float*)d_in[2];
    const float* memories  = (const float*)d_in[3];
    const float* W1 = (const float*)d_in[4];
    const float* b1 = (const float*)d_in[5];
    const float* W2 = (const float*)d_in[6];
    const float* b2 = (const float*)d_in[7];

    float* out      = (float*)d_out;
    float* outp_g   = out;                       // 16*32*64
    float* outc_g   = out + 32768;               // 16*32*256
    float* mems_out = out + 32768 + 131072;      // 16*32*256*256

    int* cnt = (int*)d_ws;                       // 16 counters

    hipMemsetAsync(cnt, 0, BB * sizeof(int), stream);
    hipLaunchKernelGGL(KF, dim3(BB * MM), dim3(256), 0, stream,
                       pointers, contents, receivers, memories, W1, b1, W2, b2,
                       outp_g, outc_g, mems_out, cnt);
}

// Round 20
// 45.447 us; speedup vs baseline: 2.1264x; 2.1264x over previous
//
#include <hip/hip_runtime.h>
#include <math.h>

#define BB 16
#define TT 128
#define MM 32
#define PP 64
#define CC 256

typedef float f32x4 __attribute__((ext_vector_type(4)));

// ---- K1: per (b,m), 512 threads: w_in, eff_c(+nrm), eff_p, matvec, MLP ----
__global__ __launch_bounds__(512) void K1_front(
        const float* __restrict__ pointers,
        const float* __restrict__ contents,
        const float* __restrict__ receivers,
        const float* __restrict__ memories,
        const float* __restrict__ W1,
        const float* __restrict__ b1,
        const float* __restrict__ W2,
        const float* __restrict__ b2,
        float* __restrict__ nrm_ws,
        float* __restrict__ outp_g,
        float* __restrict__ outc_g) {
    const int bm = blockIdx.x;
    const int b = bm >> 5, m = bm & 31;
    const int tid = threadIdx.x;
    const int lane = tid & 63, w = tid >> 6;

    __shared__ float w_in[TT];
    __shared__ __align__(16) float ri[PP + CC];   // [eff_p | eff_c]
    __shared__ float partc[4][CC];
    __shared__ float part8[8][PP];
    __shared__ float h[PP];
    __shared__ float outc_s[CC];
    __shared__ float red[4];

    // ---- w_in: 4 lanes per token, contiguous float4 reads ----
    {
        const int t = tid >> 2, q = tid & 3;
        const float4* pr4 = reinterpret_cast<const float4*>(pointers + (b * TT + t) * PP + q * 16);
        const float4* rc4 = reinterpret_cast<const float4*>(receivers + m * PP + q * 16);
        float s = 0.f;
        #pragma unroll
        for (int k = 0; k < 4; ++k) {
            float4 v = pr4[k], rv = rc4[k];
            s += v.x * rv.x + v.y * rv.y + v.z * rv.z + v.w * rv.w;
        }
        s += __shfl_xor(s, 1, 64);
        s += __shfl_xor(s, 2, 64);
        if (q == 0) {
            float th = tanhf(s);
            w_in[t] = th > 0.f ? th : 0.f;
        }
    }
    __syncthreads();
    // ---- eff_c partials: float2 column-pairs, 4 t-groups of 32 ----
    {
        const int cp = tid & 127, g = tid >> 7;
        const float2* cb2 = reinterpret_cast<const float2*>(contents + (b * TT + g * 32) * CC) + cp;
        float2 acc = {0.f, 0.f};
        #pragma unroll 8
        for (int t = 0; t < 32; ++t) {
            float2 v = cb2[t * 128];
            const float ww = w_in[g * 32 + t];
            acc.x += ww * v.x;
            acc.y += ww * v.y;
        }
        partc[g][2 * cp]     = acc.x;
        partc[g][2 * cp + 1] = acc.y;
    }
    // ---- eff_p partials: p = tid&63, 8 t-groups of 16 ----
    {
        const int p = tid & 63, g = tid >> 6;
        const float* pb = pointers + (b * TT + g * 16) * PP + p;
        float acc = 0.f;
        #pragma unroll
        for (int t = 0; t < 16; ++t) acc += w_in[g * 16 + t] * pb[t * PP];
        part8[g][p] = acc;
    }
    __syncthreads();
    float ecv = 0.f;
    if (tid < CC) {
        ecv = partc[0][tid] + partc[1][tid] + partc[2][tid] + partc[3][tid];
        ri[PP + tid] = ecv;
        float v = ecv * ecv;
        #pragma unroll
        for (int off = 32; off; off >>= 1) v += __shfl_xor(v, off, 64);
        if (lane == 0) red[w] = v;
    } else if (tid < CC + PP) {
        const int p = tid - CC;
        float a = 0.f;
        #pragma unroll
        for (int g = 0; g < 8; ++g) a += part8[g][p];
        ri[p] = a;
    }
    __syncthreads();
    if (tid < CC) {
        const float ss = red[0] + red[1] + red[2] + red[3];
        nrm_ws[bm * CC + tid] = ecv / (ss + 1e-42f);
    }

    // ---- out_c = mem[m] @ eff_c: 16 lanes/row, 4 rows per wave-iter ----
    {
        const int g = lane >> 4, j = lane & 15;
        float4 e_reg[4];
        #pragma unroll
        for (int k = 0; k < 4; ++k)
            e_reg[k] = *reinterpret_cast<const float4*>(&ri[PP + 4 * (j + 16 * k)]);
        const float4* mem4 = reinterpret_cast<const float4*>(memories) + m * (CC * CC / 4);
        #pragma unroll
        for (int i = 0; i < 8; ++i) {
            const int c = w * 32 + i * 4 + g;
            const float4* row4 = mem4 + c * 64;
            float s = 0.f;
            #pragma unroll
            for (int k = 0; k < 4; ++k) {
                float4 mv = row4[j + 16 * k];
                s += mv.x * e_reg[k].x + mv.y * e_reg[k].y
                   + mv.z * e_reg[k].z + mv.w * e_reg[k].w;
            }
            s += __shfl_xor(s, 1, 64);
            s += __shfl_xor(s, 2, 64);
            s += __shfl_xor(s, 4, 64);
            s += __shfl_xor(s, 8, 64);
            if (j == 0) outc_s[c] = s;
        }
    }

    // ---- MLP layer 1 ----
    {
        const float* w1 = W1 + m * 320 * 64;
        float acc = 0.f;
        const int i0 = w * 40;
        #pragma unroll 8
        for (int i = i0; i < i0 + 40; ++i) acc += ri[i] * w1[i * 64 + lane];
        __syncthreads();               // also covers outc_s completion
        part8[w][lane] = acc;
    }
    __syncthreads();
    if (tid < PP) {
        float s = b1[m * PP + tid];
        #pragma unroll
        for (int g = 0; g < 8; ++g) s += part8[g][tid];
        h[tid] = s > 0.f ? s : 0.f;
    }
    __syncthreads();
    // ---- MLP layer 2 ----
    {
        const float* w2 = W2 + m * 64 * 64;
        float acc = 0.f;
        const int i0 = w * 8;
        #pragma unroll
        for (int i = i0; i < i0 + 8; ++i) acc += h[i] * w2[i * 64 + lane];
        part8[w][lane] = acc;
    }
    __syncthreads();
    if (tid < PP) {
        float s = b2[m * PP + tid];
        #pragma unroll
        for (int g = 0; g < 8; ++g) s += part8[g][tid];
        outp_g[bm * PP + tid] = s > 0.f ? s : 0.f;
    }
    if (tid < CC) outc_g[bm * CC + tid] = outc_s[tid];
}

// ---- K3: fill-like stream, grid = 1024 (4 blocks/CU), 2 batches/block.
// gid = b0*128 + m*4 + cs (b0 in [0,8)); batches b0 and b0+8.
// Tile (m,cs) held in 16 f32x4 regs; same-XCD mapping (128 % 8 == 0).
__global__ __launch_bounds__(256) void K3_fused(
        const float* __restrict__ memories,
        const float* __restrict__ outp_g,
        const float* __restrict__ outc_g,
        const float* __restrict__ nrm_ws,
        float* __restrict__ mems_out) {
    const int gid0 = blockIdx.x;           // [0, 1024)
    const int b0 = gid0 >> 7;              // [0, 8)
    const int m = (gid0 >> 2) & 31, cs = gid0 & 3;
    const int tid = threadIdx.x;
    const int lane = tid & 63, w = tid >> 6;

    __shared__ float wout_s[MM];
    __shared__ float eoc_s[64];

    // ---- load the 64 KB tile ONCE into registers ----
    const f32x4* mem4 = reinterpret_cast<const f32x4*>(memories) + (m * CC + cs * 64) * 64;
    f32x4 mv[16];
    #pragma unroll
    for (int k = 0; k < 16; ++k) mv[k] = mem4[k * 256 + tid];

    for (int k2 = 0; k2 < 2; ++k2) {
        const int b = b0 + 8 * k2;
        const int bm = b * MM + m;
        if (k2) __syncthreads();           // protect LDS reuse across batches

        // nrm for this (b,m)
        const float4 nv = *reinterpret_cast<const float4*>(nrm_ws + bm * CC + lane * 4);

        // ---- wout row m: n = tid>>3, j = tid&7 ----
        {
            const int n = tid >> 3, j = tid & 7;
            const float* opm = outp_g + bm * PP + j * 8;
            const float* opn = outp_g + (b * MM + n) * PP + j * 8;
            float s = 0.f;
            #pragma unroll
            for (int k = 0; k < 8; ++k) s += opm[k] * opn[k];
            s += __shfl_xor(s, 1, 64);
            s += __shfl_xor(s, 2, 64);
            s += __shfl_xor(s, 4, 64);
            if (j == 0) {
                float th = tanhf(s);
                wout_s[n] = th > 0.f ? th : 0.f;
            }
        }
        __syncthreads();
        // ---- eoc slice (64 c's): c_local = tid>>2, k = tid&3 ----
        {
            const int c_local = tid >> 2, k = tid & 3;
            const int c = cs * 64 + c_local;
            const float* cb = outc_g + (b * MM + k * 8) * CC + c;
            float s = 0.f;
            #pragma unroll
            for (int kk = 0; kk < 8; ++kk)
                s += wout_s[k * 8 + kk] * cb[kk * CC];
            s += __shfl_xor(s, 1, 64);
            s += __shfl_xor(s, 2, 64);
            if (k == 0) eoc_s[c_local] = s;
        }
        __syncthreads();

        // ---- pure-store pass: 16 x 1 KB/wave, tile already in registers ----
        f32x4* out4 = reinterpret_cast<f32x4*>(mems_out) + (bm * CC + cs * 64) * 64;
        #pragma unroll
        for (int k = 0; k < 16; ++k) {
            const float e = eoc_s[k * 4 + w];
            f32x4 o;
            o.x = 0.5f * (mv[k].x + e * nv.x);
            o.y = 0.5f * (mv[k].y + e * nv.y);
            o.z = 0.5f * (mv[k].z + e * nv.z);
            o.w = 0.5f * (mv[k].w + e * nv.w);
            out4[k * 256 + tid] = o;
        }
    }
}

extern "C" void kernel_launch(void* const* d_in, const int* in_sizes, int n_in,
                              void* d_out, int out_size, void* d_ws, size_t ws_size,
                              hipStream_t stream) {
    const float* pointers  = (const float*)d_in[0];
    const float* contents  = (const float*)d_in[1];
    const float* receivers = (const float*)d_in[2];
    const float* memories  = (const float*)d_in[3];
    const float* W1 = (const float*)d_in[4];
    const float* b1 = (const float*)d_in[5];
    const float* W2 = (const float*)d_in[6];
    const float* b2 = (const float*)d_in[7];

    float* out      = (float*)d_out;
    float* outp_g   = out;                       // 16*32*64
    float* outc_g   = out + 32768;               // 16*32*256
    float* mems_out = out + 32768 + 131072;      // 16*32*256*256

    float* nrm = (float*)d_ws;                   // 131072 floats

    hipLaunchKernelGGL(K1_front, dim3(BB * MM), dim3(512), 0, stream,
                       pointers, contents, receivers, memories, W1, b1, W2, b2,
                       nrm, outp_g, outc_g);
    hipLaunchKernelGGL(K3_fused, dim3(1024), dim3(256), 0, stream,
                       memories, outp_g, outc_g, nrm, mems_out);
}

// Round 21
// 44.153 us; speedup vs baseline: 2.1887x; 1.0293x over previous
//
#include <hip/hip_runtime.h>
#include <math.h>

#define BB 16
#define TT 128
#define MM 32
#define PP 64
#define CC 256

typedef float f32x4 __attribute__((ext_vector_type(4)));

// ---- K1: per (b,m), 512 threads: w_in, eff_c(+nrm), eff_p, matvec, MLP ----
__global__ __launch_bounds__(512) void K1_front(
        const float* __restrict__ pointers,
        const float* __restrict__ contents,
        const float* __restrict__ receivers,
        const float* __restrict__ memories,
        const float* __restrict__ W1,
        const float* __restrict__ b1,
        const float* __restrict__ W2,
        const float* __restrict__ b2,
        float* __restrict__ nrm_ws,
        float* __restrict__ outp_g,
        float* __restrict__ outc_g) {
    const int bm = blockIdx.x;
    const int b = bm >> 5, m = bm & 31;
    const int tid = threadIdx.x;
    const int lane = tid & 63, w = tid >> 6;

    __shared__ float w_in[TT];
    __shared__ __align__(16) float ri[PP + CC];   // [eff_p | eff_c]
    __shared__ float partc[4][CC];
    __shared__ float part8[8][PP];
    __shared__ float h[PP];
    __shared__ float outc_s[CC];
    __shared__ float red[4];

    // ---- w_in: 4 lanes per token, contiguous float4 reads ----
    {
        const int t = tid >> 2, q = tid & 3;
        const float4* pr4 = reinterpret_cast<const float4*>(pointers + (b * TT + t) * PP + q * 16);
        const float4* rc4 = reinterpret_cast<const float4*>(receivers + m * PP + q * 16);
        float s = 0.f;
        #pragma unroll
        for (int k = 0; k < 4; ++k) {
            float4 v = pr4[k], rv = rc4[k];
            s += v.x * rv.x + v.y * rv.y + v.z * rv.z + v.w * rv.w;
        }
        s += __shfl_xor(s, 1, 64);
        s += __shfl_xor(s, 2, 64);
        if (q == 0) {
            float th = tanhf(s);
            w_in[t] = th > 0.f ? th : 0.f;
        }
    }
    __syncthreads();
    // ---- eff_c partials: float2 column-pairs, 4 t-groups of 32 ----
    {
        const int cp = tid & 127, g = tid >> 7;
        const float2* cb2 = reinterpret_cast<const float2*>(contents + (b * TT + g * 32) * CC) + cp;
        float2 acc = {0.f, 0.f};
        #pragma unroll 8
        for (int t = 0; t < 32; ++t) {
            float2 v = cb2[t * 128];
            const float ww = w_in[g * 32 + t];
            acc.x += ww * v.x;
            acc.y += ww * v.y;
        }
        partc[g][2 * cp]     = acc.x;
        partc[g][2 * cp + 1] = acc.y;
    }
    // ---- eff_p partials: p = tid&63, 8 t-groups of 16 ----
    {
        const int p = tid & 63, g = tid >> 6;
        const float* pb = pointers + (b * TT + g * 16) * PP + p;
        float acc = 0.f;
        #pragma unroll
        for (int t = 0; t < 16; ++t) acc += w_in[g * 16 + t] * pb[t * PP];
        part8[g][p] = acc;
    }
    __syncthreads();
    float ecv = 0.f;
    if (tid < CC) {
        ecv = partc[0][tid] + partc[1][tid] + partc[2][tid] + partc[3][tid];
        ri[PP + tid] = ecv;
        float v = ecv * ecv;
        #pragma unroll
        for (int off = 32; off; off >>= 1) v += __shfl_xor(v, off, 64);
        if (lane == 0) red[w] = v;
    } else if (tid < CC + PP) {
        const int p = tid - CC;
        float a = 0.f;
        #pragma unroll
        for (int g = 0; g < 8; ++g) a += part8[g][p];
        ri[p] = a;
    }
    __syncthreads();
    if (tid < CC) {
        const float ss = red[0] + red[1] + red[2] + red[3];
        nrm_ws[bm * CC + tid] = ecv / (ss + 1e-42f);
    }

    // ---- out_c = mem[m] @ eff_c: 16 lanes/row, 4 rows per wave-iter ----
    {
        const int g = lane >> 4, j = lane & 15;
        float4 e_reg[4];
        #pragma unroll
        for (int k = 0; k < 4; ++k)
            e_reg[k] = *reinterpret_cast<const float4*>(&ri[PP + 4 * (j + 16 * k)]);
        const float4* mem4 = reinterpret_cast<const float4*>(memories) + m * (CC * CC / 4);
        #pragma unroll
        for (int i = 0; i < 8; ++i) {
            const int c = w * 32 + i * 4 + g;
            const float4* row4 = mem4 + c * 64;
            float s = 0.f;
            #pragma unroll
            for (int k = 0; k < 4; ++k) {
                float4 mv = row4[j + 16 * k];
                s += mv.x * e_reg[k].x + mv.y * e_reg[k].y
                   + mv.z * e_reg[k].z + mv.w * e_reg[k].w;
            }
            s += __shfl_xor(s, 1, 64);
            s += __shfl_xor(s, 2, 64);
            s += __shfl_xor(s, 4, 64);
            s += __shfl_xor(s, 8, 64);
            if (j == 0) outc_s[c] = s;
        }
    }

    // ---- MLP layer 1 ----
    {
        const float* w1 = W1 + m * 320 * 64;
        float acc = 0.f;
        const int i0 = w * 40;
        #pragma unroll 8
        for (int i = i0; i < i0 + 40; ++i) acc += ri[i] * w1[i * 64 + lane];
        __syncthreads();               // also covers outc_s completion
        part8[w][lane] = acc;
    }
    __syncthreads();
    if (tid < PP) {
        float s = b1[m * PP + tid];
        #pragma unroll
        for (int g = 0; g < 8; ++g) s += part8[g][tid];
        h[tid] = s > 0.f ? s : 0.f;
    }
    __syncthreads();
    // ---- MLP layer 2 ----
    {
        const float* w2 = W2 + m * 64 * 64;
        float acc = 0.f;
        const int i0 = w * 8;
        #pragma unroll
        for (int i = i0; i < i0 + 8; ++i) acc += h[i] * w2[i * 64 + lane];
        part8[w][lane] = acc;
    }
    __syncthreads();
    if (tid < PP) {
        float s = b2[m * PP + tid];
        #pragma unroll
        for (int g = 0; g < 8; ++g) s += part8[g][tid];
        outp_g[bm * PP + tid] = s > 0.f ? s : 0.f;
    }
    if (tid < CC) outc_g[bm * CC + tid] = outc_s[tid];
}

// ---- K3: fill-like stream, 128 threads (2 waves) -> 4 waves/CU total.
// grid = 512: gid = b0*128 + m*4 + cs (b0 in [0,4)), batches b0+4*k4.
// Tile (m,cs) = 64 rows held in 32 f32x4 regs; same-XCD mapping (128%8==0).
__global__ __launch_bounds__(128) void K3_fused(
        const float* __restrict__ memories,
        const float* __restrict__ outp_g,
        const float* __restrict__ outc_g,
        const float* __restrict__ nrm_ws,
        float* __restrict__ mems_out) {
    const int gid0 = blockIdx.x;           // [0, 512)
    const int b0 = gid0 >> 7;              // [0, 4)
    const int m = (gid0 >> 2) & 31, cs = gid0 & 3;
    const int tid = threadIdx.x;           // [0, 128)
    const int lane = tid & 63, w2 = tid >> 6;   // wave 0/1

    __shared__ float wout_s[MM];
    __shared__ float eoc_s[64];

    // ---- load the 64 KB tile ONCE into registers (32 f32x4/thread) ----
    const f32x4* mem4 = reinterpret_cast<const f32x4*>(memories) + (m * CC + cs * 64) * 64;
    f32x4 mv[32];
    #pragma unroll
    for (int k = 0; k < 32; ++k) mv[k] = mem4[k * 128 + tid];

    for (int k4 = 0; k4 < 4; ++k4) {
        const int b = b0 + 4 * k4;
        const int bm = b * MM + m;
        if (k4) __syncthreads();           // protect LDS reuse across batches

        // nrm: thread's d-slot is lane (store idx (k*128+tid)&63 == lane)
        const float4 nv = *reinterpret_cast<const float4*>(nrm_ws + bm * CC + lane * 4);

        // ---- wout row m: n = tid>>2 (32 n), j = tid&3 (16 floats/lane) ----
        {
            const int n = tid >> 2, j = tid & 3;
            const float4* opm = reinterpret_cast<const float4*>(outp_g + bm * PP + j * 16);
            const float4* opn = reinterpret_cast<const float4*>(outp_g + (b * MM + n) * PP + j * 16);
            float s = 0.f;
            #pragma unroll
            for (int k = 0; k < 4; ++k) {
                float4 a = opm[k], c4 = opn[k];
                s += a.x * c4.x + a.y * c4.y + a.z * c4.z + a.w * c4.w;
            }
            s += __shfl_xor(s, 1, 64);
            s += __shfl_xor(s, 2, 64);
            if (j == 0) {
                float th = tanhf(s);
                wout_s[n] = th > 0.f ? th : 0.f;
            }
        }
        __syncthreads();
        // ---- eoc slice (64 c's): cl = tid>>1, kq = tid&1 (16 n's each) ----
        {
            const int cl = tid >> 1, kq = tid & 1;
            const int c = cs * 64 + cl;
            const float* cb = outc_g + (b * MM + kq * 16) * CC + c;
            float s = 0.f;
            #pragma unroll
            for (int kk = 0; kk < 16; ++kk)
                s += wout_s[kq * 16 + kk] * cb[kk * CC];
            s += __shfl_xor(s, 1, 64);
            if (kq == 0) eoc_s[cl] = s;
        }
        __syncthreads();

        // ---- pure-store pass: 32 x 2 KB rounds, tile in registers ----
        f32x4* out4 = reinterpret_cast<f32x4*>(mems_out) + (bm * CC + cs * 64) * 64;
        #pragma unroll
        for (int k = 0; k < 32; ++k) {
            const float e = eoc_s[k * 2 + w2];
            f32x4 o;
            o.x = 0.5f * (mv[k].x + e * nv.x);
            o.y = 0.5f * (mv[k].y + e * nv.y);
            o.z = 0.5f * (mv[k].z + e * nv.z);
            o.w = 0.5f * (mv[k].w + e * nv.w);
            out4[k * 128 + tid] = o;
        }
    }
}

extern "C" void kernel_launch(void* const* d_in, const int* in_sizes, int n_in,
                              void* d_out, int out_size, void* d_ws, size_t ws_size,
                              hipStream_t stream) {
    const float* pointers  = (const float*)d_in[0];
    const float* contents  = (const float*)d_in[1];
    const float* receivers = (const float*)d_in[2];
    const float* memories  = (const float*)d_in[3];
    const float* W1 = (const float*)d_in[4];
    const float* b1 = (const float*)d_in[5];
    const float* W2 = (const float*)d_in[6];
    const float* b2 = (const float*)d_in[7];

    float* out      = (float*)d_out;
    float* outp_g   = out;                       // 16*32*64
    float* outc_g   = out + 32768;               // 16*32*256
    float* mems_out = out + 32768 + 131072;      // 16*32*256*256

    float* nrm = (float*)d_ws;                   // 131072 floats

    hipLaunchKernelGGL(K1_front, dim3(BB * MM), dim3(512), 0, stream,
                       pointers, contents, receivers, memories, W1, b1, W2, b2,
                       nrm, outp_g, outc_g);
    hipLaunchKernelGGL(K3_fused, dim3(512), dim3(128), 0, stream,
                       memories, outp_g, outc_g, nrm, mems_out);
}

// Round 22
// 43.370 us; speedup vs baseline: 2.2283x; 1.0181x over previous
//
#include <hip/hip_runtime.h>
#include <math.h>

#define BB 16
#define TT 128
#define MM 32
#define PP 64
#define CC 256

typedef float f32x4 __attribute__((ext_vector_type(4)));

// ---- K1: per (b,m), 512 threads: w_in, eff_c(+nrm), eff_p, matvec, MLP ----
__global__ __launch_bounds__(512) void K1_front(
        const float* __restrict__ pointers,
        const float* __restrict__ contents,
        const float* __restrict__ receivers,
        const float* __restrict__ memories,
        const float* __restrict__ W1,
        const float* __restrict__ b1,
        const float* __restrict__ W2,
        const float* __restrict__ b2,
        float* __restrict__ nrm_ws,
        float* __restrict__ outp_g,
        float* __restrict__ outc_g) {
    const int bm = blockIdx.x;
    const int b = bm >> 5, m = bm & 31;
    const int tid = threadIdx.x;
    const int lane = tid & 63, w = tid >> 6;

    __shared__ float w_in[TT];
    __shared__ __align__(16) float ri[PP + CC];   // [eff_p | eff_c]
    __shared__ float partc[4][CC];
    __shared__ float part8[8][PP];
    __shared__ float h[PP];
    __shared__ float outc_s[CC];
    __shared__ float red[4];

    // ---- w_in: 4 lanes per token, contiguous float4 reads ----
    {
        const int t = tid >> 2, q = tid & 3;
        const float4* pr4 = reinterpret_cast<const float4*>(pointers + (b * TT + t) * PP + q * 16);
        const float4* rc4 = reinterpret_cast<const float4*>(receivers + m * PP + q * 16);
        float s = 0.f;
        #pragma unroll
        for (int k = 0; k < 4; ++k) {
            float4 v = pr4[k], rv = rc4[k];
            s += v.x * rv.x + v.y * rv.y + v.z * rv.z + v.w * rv.w;
        }
        s += __shfl_xor(s, 1, 64);
        s += __shfl_xor(s, 2, 64);
        if (q == 0) {
            float th = tanhf(s);
            w_in[t] = th > 0.f ? th : 0.f;
        }
    }
    __syncthreads();
    // ---- eff_c partials: float2 column-pairs, 4 t-groups of 32 ----
    {
        const int cp = tid & 127, g = tid >> 7;
        const float2* cb2 = reinterpret_cast<const float2*>(contents + (b * TT + g * 32) * CC) + cp;
        float2 acc = {0.f, 0.f};
        #pragma unroll 8
        for (int t = 0; t < 32; ++t) {
            float2 v = cb2[t * 128];
            const float ww = w_in[g * 32 + t];
            acc.x += ww * v.x;
            acc.y += ww * v.y;
        }
        partc[g][2 * cp]     = acc.x;
        partc[g][2 * cp + 1] = acc.y;
    }
    // ---- eff_p partials: p = tid&63, 8 t-groups of 16 ----
    {
        const int p = tid & 63, g = tid >> 6;
        const float* pb = pointers + (b * TT + g * 16) * PP + p;
        float acc = 0.f;
        #pragma unroll
        for (int t = 0; t < 16; ++t) acc += w_in[g * 16 + t] * pb[t * PP];
        part8[g][p] = acc;
    }
    __syncthreads();
    float ecv = 0.f;
    if (tid < CC) {
        ecv = partc[0][tid] + partc[1][tid] + partc[2][tid] + partc[3][tid];
        ri[PP + tid] = ecv;
        float v = ecv * ecv;
        #pragma unroll
        for (int off = 32; off; off >>= 1) v += __shfl_xor(v, off, 64);
        if (lane == 0) red[w] = v;
    } else if (tid < CC + PP) {
        const int p = tid - CC;
        float a = 0.f;
        #pragma unroll
        for (int g = 0; g < 8; ++g) a += part8[g][p];
        ri[p] = a;
    }
    __syncthreads();
    if (tid < CC) {
        const float ss = red[0] + red[1] + red[2] + red[3];
        nrm_ws[bm * CC + tid] = ecv / (ss + 1e-42f);
    }

    // ---- out_c = mem[m] @ eff_c: 16 lanes/row, 4 rows per wave-iter ----
    {
        const int g = lane >> 4, j = lane & 15;
        float4 e_reg[4];
        #pragma unroll
        for (int k = 0; k < 4; ++k)
            e_reg[k] = *reinterpret_cast<const float4*>(&ri[PP + 4 * (j + 16 * k)]);
        const float4* mem4 = reinterpret_cast<const float4*>(memories) + m * (CC * CC / 4);
        #pragma unroll
        for (int i = 0; i < 8; ++i) {
            const int c = w * 32 + i * 4 + g;
            const float4* row4 = mem4 + c * 64;
            float s = 0.f;
            #pragma unroll
            for (int k = 0; k < 4; ++k) {
                float4 mv = row4[j + 16 * k];
                s += mv.x * e_reg[k].x + mv.y * e_reg[k].y
                   + mv.z * e_reg[k].z + mv.w * e_reg[k].w;
            }
            s += __shfl_xor(s, 1, 64);
            s += __shfl_xor(s, 2, 64);
            s += __shfl_xor(s, 4, 64);
            s += __shfl_xor(s, 8, 64);
            if (j == 0) outc_s[c] = s;
        }
    }

    // ---- MLP layer 1 ----
    {
        const float* w1 = W1 + m * 320 * 64;
        float acc = 0.f;
        const int i0 = w * 40;
        #pragma unroll 8
        for (int i = i0; i < i0 + 40; ++i) acc += ri[i] * w1[i * 64 + lane];
        __syncthreads();               // also covers outc_s completion
        part8[w][lane] = acc;
    }
    __syncthreads();
    if (tid < PP) {
        float s = b1[m * PP + tid];
        #pragma unroll
        for (int g = 0; g < 8; ++g) s += part8[g][tid];
        h[tid] = s > 0.f ? s : 0.f;
    }
    __syncthreads();
    // ---- MLP layer 2 ----
    {
        const float* w2 = W2 + m * 64 * 64;
        float acc = 0.f;
        const int i0 = w * 8;
        #pragma unroll
        for (int i = i0; i < i0 + 8; ++i) acc += h[i] * w2[i * 64 + lane];
        part8[w][lane] = acc;
    }
    __syncthreads();
    if (tid < PP) {
        float s = b2[m * PP + tid];
        #pragma unroll
        for (int g = 0; g < 8; ++g) s += part8[g][tid];
        outp_g[bm * PP + tid] = s > 0.f ? s : 0.f;
    }
    if (tid < CC) outc_g[bm * CC + tid] = outc_s[tid];
}

// ---- K3: fill-like stream. grid = 512 blocks (2/CU), 256 threads.
// Block owns one (m,cs) 64-row tile, held in 16 f32x4 registers, and loops
// over 4 batches b = b0 + 4*k4: {wout row, eoc slice, pure-store pass}.
// Same-XCD mapping preserved (blocks sharing (m,cs) are 128 apart).
__global__ __launch_bounds__(256) void K3_fused(
        const float* __restrict__ memories,
        const float* __restrict__ outp_g,
        const float* __restrict__ outc_g,
        const float* __restrict__ nrm_ws,
        float* __restrict__ mems_out) {
    const int gid0 = blockIdx.x;           // [0, 512)
    const int b0 = gid0 >> 7;              // [0, 4)
    const int m = (gid0 >> 2) & 31, cs = gid0 & 3;
    const int tid = threadIdx.x;
    const int lane = tid & 63, w = tid >> 6;

    __shared__ float wout_s[MM];
    __shared__ float eoc_s[64];

    // ---- load the 64 KB tile ONCE into registers ----
    const f32x4* mem4 = reinterpret_cast<const f32x4*>(memories) + (m * CC + cs * 64) * 64;
    f32x4 mv[16];
    #pragma unroll
    for (int k = 0; k < 16; ++k) mv[k] = mem4[k * 256 + tid];

    for (int k4 = 0; k4 < 4; ++k4) {
        const int b = b0 + 4 * k4;
        const int bm = b * MM + m;
        if (k4) __syncthreads();           // protect LDS reuse across batches

        // nrm for this (b,m)
        const float4 nv = *reinterpret_cast<const float4*>(nrm_ws + bm * CC + lane * 4);

        // ---- wout row m: n = tid>>3, j = tid&7 ----
        {
            const int n = tid >> 3, j = tid & 7;
            const float* opm = outp_g + bm * PP + j * 8;
            const float* opn = outp_g + (b * MM + n) * PP + j * 8;
            float s = 0.f;
            #pragma unroll
            for (int k = 0; k < 8; ++k) s += opm[k] * opn[k];
            s += __shfl_xor(s, 1, 64);
            s += __shfl_xor(s, 2, 64);
            s += __shfl_xor(s, 4, 64);
            if (j == 0) {
                float th = tanhf(s);
                wout_s[n] = th > 0.f ? th : 0.f;
            }
        }
        __syncthreads();
        // ---- eoc slice (64 c's): c_local = tid>>2, k = tid&3 ----
        {
            const int c_local = tid >> 2, k = tid & 3;
            const int c = cs * 64 + c_local;
            const float* cb = outc_g + (b * MM + k * 8) * CC + c;
            float s = 0.f;
            #pragma unroll
            for (int kk = 0; kk < 8; ++kk)
                s += wout_s[k * 8 + kk] * cb[kk * CC];
            s += __shfl_xor(s, 1, 64);
            s += __shfl_xor(s, 2, 64);
            if (k == 0) eoc_s[c_local] = s;
        }
        __syncthreads();

        // ---- pure-store pass: 16 x 1 KB/wave, tile already in registers ----
        f32x4* out4 = reinterpret_cast<f32x4*>(mems_out) + (bm * CC + cs * 64) * 64;
        #pragma unroll
        for (int k = 0; k < 16; ++k) {
            const float e = eoc_s[k * 4 + w];
            f32x4 o;
            o.x = 0.5f * (mv[k].x + e * nv.x);
            o.y = 0.5f * (mv[k].y + e * nv.y);
            o.z = 0.5f * (mv[k].z + e * nv.z);
            o.w = 0.5f * (mv[k].w + e * nv.w);
            out4[k * 256 + tid] = o;
        }
    }
}

extern "C" void kernel_launch(void* const* d_in, const int* in_sizes, int n_in,
                              void* d_out, int out_size, void* d_ws, size_t ws_size,
                              hipStream_t stream) {
    const float* pointers  = (const float*)d_in[0];
    const float* contents  = (const float*)d_in[1];
    const float* receivers = (const float*)d_in[2];
    const float* memories  = (const float*)d_in[3];
    const float* W1 = (const float*)d_in[4];
    const float* b1 = (const float*)d_in[5];
    const float* W2 = (const float*)d_in[6];
    const float* b2 = (const float*)d_in[7];

    float* out      = (float*)d_out;
    float* outp_g   = out;                       // 16*32*64
    float* outc_g   = out + 32768;               // 16*32*256
    float* mems_out = out + 32768 + 131072;      // 16*32*256*256

    float* nrm = (float*)d_ws;                   // 131072 floats

    hipLaunchKernelGGL(K1_front, dim3(BB * MM), dim3(512), 0, stream,
                       pointers, contents, receivers, memories, W1, b1, W2, b2,
                       nrm, outp_g, outc_g);
    hipLaunchKernelGGL(K3_fused, dim3(512), dim3(256), 0, stream,
                       memories, outp_g, outc_g, nrm, mems_out);
}